// Round 1
// baseline (512.779 us; speedup 1.0000x reference)
//
#include <hip/hip_runtime.h>
#include <math.h>

#define NT 128        // trees
#define NB 1024       // batch
#define ND 784        // feature dim
#define NK 200        // top-k
#define ND4 196       // ND / 4

// ---------------------------------------------------------------------------
// Kernel 1: per-tree top-K sparse sigmoid attention.
// One block per tree. Radix-select (MSB-first) on order-preserving uint keys
// finds the K-th largest value p and the tie count; keep u>p plus the
// lowest-index ties. sigmoid is monotonic, so top-k(sigmoid(m)) == top-k(m).
// ---------------------------------------------------------------------------
__global__ __launch_bounds__(256) void topk_attention_kernel(
    const float* __restrict__ mask, float* __restrict__ att_out)
{
    __shared__ unsigned int su[ND];
    __shared__ float        sv[ND];
    __shared__ unsigned char sel[ND];
    __shared__ int          cnts[32];   // one slot per bit -> 1 barrier/iter

    const int t   = blockIdx.x;
    const int tid = threadIdx.x;

    if (tid < 32) cnts[tid] = 0;

    for (int d = tid; d < ND; d += 256) {
        float f = mask[t * ND + d];
        unsigned int b = __float_as_uint(f);
        su[d]  = ((int)b < 0) ? ~b : (b | 0x80000000u);  // order-preserving
        sv[d]  = 1.0f / (1.0f + expf(-f));
        sel[d] = 0;
    }
    __syncthreads();

    unsigned int p = 0;   // prefix of K-th largest key (uniform across block)
    int need = NK;        // how many still to take among current candidates
    for (int bit = 31; bit >= 0; --bit) {
        const unsigned int test = (p | (1u << bit)) >> bit;
        int local = 0;
        for (int d = tid; d < ND; d += 256)
            local += ((su[d] >> bit) == test) ? 1 : 0;
        #pragma unroll
        for (int off = 32; off > 0; off >>= 1)
            local += __shfl_down(local, off);
        if ((tid & 63) == 0) atomicAdd(&cnts[bit], local);
        __syncthreads();
        const int c = cnts[bit];        // uniform read; slot never reused
        if (c >= need) p |= (1u << bit);
        else           need -= c;
    }

    // keep strictly-greater in parallel
    for (int d = tid; d < ND; d += 256)
        sel[d] = (su[d] > p) ? 1 : 0;
    __syncthreads();
    // lowest-index ties, serial on thread 0 (ties ~never happen; cheap anyway)
    if (tid == 0) {
        int rem = need;
        for (int d = 0; d < ND && rem > 0; ++d)
            if (su[d] == p) { sel[d] = 1; --rem; }
    }
    __syncthreads();

    for (int d = tid; d < ND; d += 256)
        att_out[t * ND + d] = sel[d] ? sv[d] : 0.0f;
}

// ---------------------------------------------------------------------------
// Kernel 2: out[b,t,d] = x[b,d] * att[t,d], float4-vectorized, write-bound.
// Flat index over B*T*ND4 float4s; grid-stride x4 to amortize setup.
// ---------------------------------------------------------------------------
__global__ __launch_bounds__(256) void bcast_mul_kernel(
    const float4* __restrict__ x4, const float4* __restrict__ att4,
    float4* __restrict__ out4)
{
    const int total4 = NB * NT * ND4;                 // 25,690,112
    const int stride = gridDim.x * blockDim.x;
    for (int idx = blockIdx.x * 256 + threadIdx.x; idx < total4; idx += stride) {
        const int bt = idx / ND4;                     // magic-mul, cheap
        const int d4 = idx - bt * ND4;
        const int t  = bt & (NT - 1);
        const int b  = bt >> 7;
        const float4 xv = x4[b * ND4 + d4];
        const float4 av = att4[t * ND4 + d4];
        float4 o;
        o.x = xv.x * av.x; o.y = xv.y * av.y;
        o.z = xv.z * av.z; o.w = xv.w * av.w;
        out4[idx] = o;
    }
}

extern "C" void kernel_launch(void* const* d_in, const int* in_sizes, int n_in,
                              void* d_out, int out_size, void* d_ws, size_t ws_size,
                              hipStream_t stream)
{
    (void)in_sizes; (void)n_in; (void)out_size; (void)d_ws; (void)ws_size;
    const float* x    = (const float*)d_in[0];
    const float* mask = (const float*)d_in[1];
    float* out = (float*)d_out;
    float* att = out + (size_t)NB * NT * ND;   // attention output region

    topk_attention_kernel<<<NT, 256, 0, stream>>>(mask, att);

    const int total4 = NB * NT * ND4;
    const int grid   = total4 / (256 * 4);     // 25088 blocks, 4 f4/thread
    bcast_mul_kernel<<<grid, 256, 0, stream>>>(
        (const float4*)x, (const float4*)att, (float4*)out);
}

// Round 3
// 483.683 us; speedup vs baseline: 1.0602x; 1.0602x over previous
//
#include <hip/hip_runtime.h>
#include <math.h>

#define NT 128        // trees
#define NB 1024       // batch
#define ND 784        // feature dim
#define NK 200        // top-k
#define ND4 196       // ND / 4

typedef float vfloat4 __attribute__((ext_vector_type(4)));   // builtin-friendly

// ---------------------------------------------------------------------------
// Kernel 1: per-tree top-K sparse sigmoid attention (radix-select).
// One block per tree; sigmoid is monotonic so top-k(sigmoid(m)) == top-k(m).
// ---------------------------------------------------------------------------
__global__ __launch_bounds__(256) void topk_attention_kernel(
    const float* __restrict__ mask, float* __restrict__ att_out)
{
    __shared__ unsigned int su[ND];
    __shared__ float        sv[ND];
    __shared__ unsigned char sel[ND];
    __shared__ int          cnts[32];   // one slot per bit -> 1 barrier/iter

    const int t   = blockIdx.x;
    const int tid = threadIdx.x;

    if (tid < 32) cnts[tid] = 0;

    for (int d = tid; d < ND; d += 256) {
        float f = mask[t * ND + d];
        unsigned int b = __float_as_uint(f);
        su[d]  = ((int)b < 0) ? ~b : (b | 0x80000000u);  // order-preserving
        sv[d]  = 1.0f / (1.0f + expf(-f));
        sel[d] = 0;
    }
    __syncthreads();

    unsigned int p = 0;   // prefix of K-th largest key (uniform across block)
    int need = NK;
    for (int bit = 31; bit >= 0; --bit) {
        const unsigned int test = (p | (1u << bit)) >> bit;
        int local = 0;
        for (int d = tid; d < ND; d += 256)
            local += ((su[d] >> bit) == test) ? 1 : 0;
        #pragma unroll
        for (int off = 32; off > 0; off >>= 1)
            local += __shfl_down(local, off);
        if ((tid & 63) == 0) atomicAdd(&cnts[bit], local);
        __syncthreads();
        const int c = cnts[bit];
        if (c >= need) p |= (1u << bit);
        else           need -= c;
    }

    for (int d = tid; d < ND; d += 256)
        sel[d] = (su[d] > p) ? 1 : 0;
    __syncthreads();
    if (tid == 0) {                      // lowest-index ties (≈never)
        int rem = need;
        for (int d = 0; d < ND && rem > 0; ++d)
            if (su[d] == p) { sel[d] = 1; --rem; }
    }
    __syncthreads();

    for (int d = tid; d < ND; d += 256)
        att_out[t * ND + d] = sel[d] ? sv[d] : 0.0f;
}

// ---------------------------------------------------------------------------
// Kernel 2: one block per batch row b. x row staged in LDS (read once),
// att read block-linearly (L2-resident, coalesced), out written with
// NONTEMPORAL stores so the 411 MB stream doesn't evict x/att from L2.
// out[b, i] = x_lds[i % ND4] * att[i],  i in [0, NT*ND4)
// ---------------------------------------------------------------------------
__global__ __launch_bounds__(256) void bcast_mul_kernel(
    const vfloat4* __restrict__ x4, const vfloat4* __restrict__ att4,
    vfloat4* __restrict__ out4)
{
    __shared__ vfloat4 sx[ND4];
    const int b   = blockIdx.x;
    const int tid = threadIdx.x;
    if (tid < ND4) sx[tid] = x4[b * ND4 + tid];
    __syncthreads();

    vfloat4* __restrict__ outb = out4 + (size_t)b * (NT * ND4);
    #pragma unroll 2
    for (int i = tid; i < NT * ND4; i += 256) {   // 25088/256 = 98 iters exact
        const int t  = i / ND4;                   // magic-mul
        const int d4 = i - t * ND4;
        const vfloat4 av = att4[i];
        const vfloat4 xv = sx[d4];
        const vfloat4 o  = xv * av;
        __builtin_nontemporal_store(o, &outb[i]);
    }
}

extern "C" void kernel_launch(void* const* d_in, const int* in_sizes, int n_in,
                              void* d_out, int out_size, void* d_ws, size_t ws_size,
                              hipStream_t stream)
{
    (void)in_sizes; (void)n_in; (void)out_size; (void)d_ws; (void)ws_size;
    const float* x    = (const float*)d_in[0];
    const float* mask = (const float*)d_in[1];
    float* out = (float*)d_out;
    float* att = out + (size_t)NB * NT * ND;   // attention output region

    topk_attention_kernel<<<NT, 256, 0, stream>>>(mask, att);

    bcast_mul_kernel<<<NB, 256, 0, stream>>>(
        (const vfloat4*)x, (const vfloat4*)att, (vfloat4*)out);
}

// Round 4
// 421.848 us; speedup vs baseline: 1.2156x; 1.1466x over previous
//
#include <hip/hip_runtime.h>
#include <math.h>

#define NT 128        // trees
#define NB 1024       // batch
#define ND 784        // feature dim
#define NK 200        // top-k
#define ND4 196       // ND / 4
#define UB 7          // bcast pipeline batch (98 iters = 14 batches of 7)

typedef float vfloat4 __attribute__((ext_vector_type(4)));

// ---------------------------------------------------------------------------
// Kernel 1 v2: per-tree top-K, register-resident radix select.
// Block per tree, 256 threads; each thread owns 4 keys in VGPRs (no LDS reads
// in the 32-bit loop). One barrier per bit via [32][4] slot array. Tie-pick
// (lowest index first, matches lax.top_k) via ballot+popcount ordered rank —
// no serial scan. sigmoid monotonic => top-k(sigmoid(m)) == top-k(m).
// ---------------------------------------------------------------------------
__global__ __launch_bounds__(256) void topk_attention_kernel(
    const float* __restrict__ mask, float* __restrict__ att_out)
{
    __shared__ int wsum[32][4];
    __shared__ int wtie[4][4];

    const int t    = blockIdx.x;
    const int tid  = threadIdx.x;
    const int wave = tid >> 6;
    const int lane = tid & 63;

    unsigned int key[4];
    float        val[4];
    #pragma unroll
    for (int j = 0; j < 4; ++j) {
        const int d = tid + j * 256;
        if (d < ND) {
            const float f = mask[t * ND + d];
            const unsigned int b = __float_as_uint(f);
            key[j] = ((int)b < 0) ? ~b : (b | 0x80000000u);  // order-preserving
            val[j] = 1.0f / (1.0f + expf(-f));
        } else { key[j] = 0u; val[j] = 0.0f; }               // pad: never selected
    }

    unsigned int p = 0;
    int need = NK;
    for (int bit = 31; bit >= 0; --bit) {
        const unsigned int test = (p >> bit) | 1u;
        int c = 0;
        #pragma unroll
        for (int j = 0; j < 4; ++j) c += ((key[j] >> bit) == test) ? 1 : 0;
        #pragma unroll
        for (int off = 32; off > 0; off >>= 1) c += __shfl_down(c, off);
        if (lane == 0) wsum[bit][wave] = c;
        __syncthreads();
        const int tot = wsum[bit][0] + wsum[bit][1] + wsum[bit][2] + wsum[bit][3];
        if (tot >= need) p |= (1u << bit);
        else             need -= tot;
    }

    // ordered tie ranks: ascending d == ascending (j, wave, lane)
    int rankw[4];
    #pragma unroll
    for (int j = 0; j < 4; ++j) {
        const bool tie = (key[j] == p);
        const unsigned long long m = __ballot(tie);
        rankw[j] = __popcll(m & ((1ull << lane) - 1ull));
        if (lane == 0) wtie[j][wave] = __popcll(m);
    }
    __syncthreads();
    int jbase[4];
    {
        int pre = 0;
        #pragma unroll
        for (int j = 0; j < 4; ++j) {
            jbase[j] = pre;
            pre += wtie[j][0] + wtie[j][1] + wtie[j][2] + wtie[j][3];
        }
    }

    #pragma unroll
    for (int j = 0; j < 4; ++j) {
        const int d = tid + j * 256;
        if (d < ND) {
            bool keep = key[j] > p;
            if (key[j] == p) {
                int off = jbase[j] + rankw[j];
                for (int w = 0; w < 4; ++w) if (w < wave) off += wtie[j][w];
                keep = off < need;
            }
            att_out[t * ND + d] = keep ? val[j] : 0.0f;
        }
    }
}

// ---------------------------------------------------------------------------
// Kernel 2 v3: block per batch row b; x row in LDS; att prefetched in
// register batches of UB with loads issued BEFORE the previous batch's
// stores, so the load-consume s_waitcnt never drains outstanding nt stores
// (loads+stores share one in-order vmcnt queue on CDNA).
// ---------------------------------------------------------------------------
__global__ __launch_bounds__(256) void bcast_mul_kernel(
    const vfloat4* __restrict__ x4, const vfloat4* __restrict__ att4,
    vfloat4* __restrict__ out4)
{
    __shared__ vfloat4 sx[ND4];
    const int b   = blockIdx.x;
    const int tid = threadIdx.x;
    if (tid < ND4) sx[tid] = x4[b * ND4 + tid];
    __syncthreads();

    vfloat4* __restrict__ outb = out4 + (size_t)b * (NT * ND4);

    vfloat4 cur[UB];
    #pragma unroll
    for (int u = 0; u < UB; ++u) cur[u] = att4[tid + u * 256];

    int d4 = (tid >= ND4) ? tid - ND4 : tid;   // (tid + 256k) mod 196, k=0

    for (int nb = 0; nb < 13; ++nb) {          // batches 0..12 prefetch next
        vfloat4 nxt[UB];
        const int kb = nb * UB;
        #pragma unroll
        for (int u = 0; u < UB; ++u) nxt[u] = att4[tid + (kb + UB + u) * 256];
        #pragma unroll
        for (int u = 0; u < UB; ++u) {
            const vfloat4 o = cur[u] * sx[d4];
            __builtin_nontemporal_store(o, &outb[tid + (kb + u) * 256]);
            d4 += 60; if (d4 >= ND4) d4 -= ND4;   // (i+256) mod 196
        }
        #pragma unroll
        for (int u = 0; u < UB; ++u) cur[u] = nxt[u];
    }
    // final batch (13): stores only
    #pragma unroll
    for (int u = 0; u < UB; ++u) {
        const vfloat4 o = cur[u] * sx[d4];
        __builtin_nontemporal_store(o, &outb[tid + (13 * UB + u) * 256]);
        d4 += 60; if (d4 >= ND4) d4 -= ND4;
    }
}

extern "C" void kernel_launch(void* const* d_in, const int* in_sizes, int n_in,
                              void* d_out, int out_size, void* d_ws, size_t ws_size,
                              hipStream_t stream)
{
    (void)in_sizes; (void)n_in; (void)out_size; (void)d_ws; (void)ws_size;
    const float* x    = (const float*)d_in[0];
    const float* mask = (const float*)d_in[1];
    float* out = (float*)d_out;
    float* att = out + (size_t)NB * NT * ND;   // attention output region

    topk_attention_kernel<<<NT, 256, 0, stream>>>(mask, att);
    bcast_mul_kernel<<<NB, 256, 0, stream>>>(
        (const vfloat4*)x, (const vfloat4*)att, (vfloat4*)out);
}